// Round 5
// baseline (26.549 us; speedup 1.0000x reference)
//
#include <hip/hip_runtime.h>
#include <math.h>

#define PI_F    3.14159265358979323846f
#define TWO_PI  6.28318530717958647692f
#define HALF_PI 1.57079632679489661923f

__device__ __forceinline__ float frcp(float x)  { return __builtin_amdgcn_rcpf(x); }
__device__ __forceinline__ float frsq(float x)  { return __builtin_amdgcn_rsqf(x); }
__device__ __forceinline__ float fsqrt(float x) { return __builtin_amdgcn_sqrtf(x); }

// atan2(y,x) mapped to [0, 2pi). A&S 4.4.49 poly, |err| <= 1e-5 rad.
__device__ __forceinline__ float fast_atan2_2pi(float y, float x) {
    float ax = fabsf(x), ay = fabsf(y);
    float mx = fmaxf(ax, ay), mn = fminf(ax, ay);
    float a  = (mx > 0.0f) ? mn * frcp(mx) : 0.0f;
    float s  = a * a;
    float r  = fmaf(s, fmaf(s, fmaf(s, fmaf(s, 0.0208351f, -0.085133f),
                                    0.180141f), -0.3302995f), 0.9998660f) * a;
    if (ay > ax) r = HALF_PI - r;
    if (x < 0.0f) r = PI_F - r;
    return (y < 0.0f) ? (TWO_PI - r) : r;
}

// Four items per wave: 16-lane group per item; lane j (0..15) handles
// mixture components 4j..4j+3 (K=64). cond rows are staged coalesced
// through wave-private LDS (no barriers). Per-component math reduced to
// 4 dot products + scalar chain via x.v=0, y.v=0, w.r=-(x.w)/|x|.
__global__ __launch_bounds__(448)
void mobius_fwd(const float* __restrict__ rot,
                const float* __restrict__ cond,
                const void* __restrict__ perm,
                float* __restrict__ out,
                int B, int N)
{
    const int wave = threadIdx.x >> 6;
    const int lane = threadIdx.x & 63;
    const int sub  = lane >> 4;      // which of 4 items in the wave
    const int j    = lane & 15;      // 16-lane slot within item
    const int nwav = blockDim.x >> 6;

    const int b0     = blockIdx.x * 4;
    const int nb     = min(4, B - b0);
    const int nit    = N * nb;              // 84 when full
    const int nquads = (nit + 3) >> 2;      // 21 when full

    // permute: accept int32 or int64 delivery.
    const int* pi = (const int*)perm;
    int p0 = pi[0], p1 = pi[1], p2 = pi[2];
    bool pok = ((unsigned)p0 < 3u) && ((unsigned)p1 < 3u) && ((unsigned)p2 < 3u)
               && (p0 != p1) && (p0 != p2) && (p1 != p2);
    if (!pok) {
        const long long* pl = (const long long*)perm;
        p0 = (int)pl[0]; p1 = (int)pl[1]; p2 = (int)pl[2];
    }
    const int dd = p1 - p0;
    const bool swapc = (dd == 1 || dd == -2);

    // wave-private staging: stride 264 (not 256) so the four 16-lane groups
    // land on different bank phases (2-way max on ds_read_b128).
    __shared__ __align__(16) float smem[7][4][264];
    __shared__ float s_ldj[256];

    const size_t base_item = (size_t)b0 * N;

    for (int q = wave; q < nquads; q += nwav) {
        // ---- stage the 4 cond rows, coalesced (64 lanes x 16B each) ----
        float4 stg0, stg1, stg2, stg3;
        {
            int s0i = min(4 * q + 0, nit - 1);
            int s1i = min(4 * q + 1, nit - 1);
            int s2i = min(4 * q + 2, nit - 1);
            int s3i = min(4 * q + 3, nit - 1);
            stg0 = ((const float4*)(cond + (base_item + s0i) * 256))[lane];
            stg1 = ((const float4*)(cond + (base_item + s1i) * 256))[lane];
            stg2 = ((const float4*)(cond + (base_item + s2i) * 256))[lane];
            stg3 = ((const float4*)(cond + (base_item + s3i) * 256))[lane];
        }

        const int  i0    = 4 * q + sub;
        const bool valid = (i0 < nit);
        const int  iv    = valid ? i0 : 0;
        const size_t item = base_item + iv;

        // rot columns p0 (x) and p1 (y), raw
        const float* R = rot + item * 9;
        float x0 = R[p0], x1 = R[3 + p0], x2 = R[6 + p0];
        float y0 = R[p1], y1 = R[3 + p1], y2 = R[6 + p1];

        // per-item scalars
        float xn2    = x0 * x0 + x1 * x1 + x2 * x2;
        float inv_xn = frsq(xn2);
        float xn     = xn2 * inv_xn;
        float xy     = x0 * y0 + x1 * y1 + x2 * y2;
        float yn2    = y0 * y0 + y1 * y1 + y2 * y2;
        float negA   = yn2 - 2.0f;

        // v = normalize(cross(y, r)) = normalize(x cross y)   (r = -x/|x|)
        float cv0 = x1 * y2 - x2 * y1;
        float cv1 = x2 * y0 - x0 * y2;
        float cv2 = x0 * y1 - x1 * y0;
        float inv_cn = frsq(cv0 * cv0 + cv1 * cv1 + cv2 * cv2);
        float v0 = cv0 * inv_cn, v1 = cv1 * inv_cn, v2 = cv2 * inv_cn;

        // ---- LDS write (wave-private; in-order DS pipe, no barrier) ----
        *(float4*)&smem[wave][0][4 * lane] = stg0;
        *(float4*)&smem[wave][1][4 * lane] = stg1;
        *(float4*)&smem[wave][2][4 * lane] = stg2;
        *(float4*)&smem[wave][3][4 * lane] = stg3;

        // ---- read my 4 components (16 floats) ----
        const float* myl = &smem[wave][sub][0];
        float4 pw4 = *(const float4*)(myl + 4 * j);
        float4 fa  = *(const float4*)(myl + 64 + 12 * j);
        float4 fb  = *(const float4*)(myl + 68 + 12 * j);
        float4 fc  = *(const float4*)(myl + 72 + 12 * j);

        float PW[4] = {pw4.x, pw4.y, pw4.z, pw4.w};
        float W0[4] = {fa.x, fa.w, fb.z, fc.y};
        float W1[4] = {fa.y, fb.x, fb.w, fc.z};
        float W2[4] = {fa.z, fb.y, fc.x, fc.w};

        float pp = 0.0f, pa = 0.0f, pd = 0.0f;
        #pragma unroll
        for (int cc = 0; cc < 4; ++cc) {
            float w0 = W0[cc], w1 = W1[cc], w2 = W2[cc];
            float yw  = y0 * w0 + y1 * w1 + y2 * w2;
            float wp2 = w0 * w0 + w1 * w1 + w2 * w2;
            float xwp = x0 * w0 + x1 * w1 + x2 * w2;
            float vwp = v0 * w0 + v1 * w1 + v2 * w2;
            // ||proj w||^2 = wp2 + yw^2*(yn2-2); guard rounding cancellation
            float qn  = fmaxf(fmaf(yw * yw, negA, wp2), 0.0f);
            float sc  = 0.7f * frcp(1.0f + fsqrt(qn));
            float wn2 = (sc * sc) * qn;
            float xw  = sc * fmaf(-xy, yw, xwp);       // x . w
            float zwn2 = fmaf(-2.0f, xw, xn2 + wn2);   // ||x-w||^2
            float c   = (1.0f - wn2) * frcp(zwn2);
            float cp1 = c + 1.0f;
            float hv  = -(cp1 * (sc * vwp));           // h.v
            float hr  = fmaf(cp1, xw * inv_xn, -(c * xn)); // h.r
            float ang = fast_atan2_2pi(hv, hr);
            float p   = __logf(1.0f + __expf(PW[cc])); // softplus (|pw|<~6)
            pp += p; pa = fmaf(p, ang, pa); pd = fmaf(p, c, pd);
        }

        // butterfly within each 16-lane group; sum lands in ALL lanes
        #pragma unroll
        for (int off = 8; off >= 1; off >>= 1) {
            pp += __shfl_xor(pp, off, 64);
            pa += __shfl_xor(pa, off, 64);
            pd += __shfl_xor(pd, off, 64);
        }

        // epilogue in all lanes (redundant but same wave cycles)
        float ip   = frcp(pp);
        float angT = pa * ip;
        float ldj  = __logf(pd * ip);

        float sa, ca;
        __sincosf(angT, &sa, &ca);
        float r0 = -x0 * inv_xn, r1 = -x1 * inv_xn, r2 = -x2 * inv_xn;
        float t0 = fmaf(r0, ca, v0 * sa);
        float t1 = fmaf(r1, ca, v1 * sa);
        float t2 = fmaf(r2, ca, v2 * sa);

        float u0, u1, u2;
        if (swapc) {               // tz = cross(tx, y)
            u0 = t1 * y2 - t2 * y1;
            u1 = t2 * y0 - t0 * y2;
            u2 = t0 * y1 - t1 * y0;
        } else {                   // tz = cross(y, tx)
            u0 = y1 * t2 - y2 * t1;
            u1 = y2 * t0 - y0 * t2;
            u2 = y0 * t1 - y1 * t0;
        }
        float iun = frsq(u0 * u0 + u1 * u1 + u2 * u2);
        u0 *= iun; u1 *= iun; u2 *= iun;

        if (valid) {
            if (j < 9) {
                int row = (j >= 6) ? 2 : (j >= 3) ? 1 : 0;
                int cp  = j - 3 * row;
                float tr = (row == 0) ? t0 : (row == 1) ? t1 : t2;
                float yr = (row == 0) ? y0 : (row == 1) ? y1 : y2;
                float ur = (row == 0) ? u0 : (row == 1) ? u1 : u2;
                float val = (cp == p0) ? tr : (cp == p1) ? yr : ur;
                out[item * 9 + j] = val;
            }
            if (j == 0) s_ldj[i0] = ldj;
        }
    }

    __syncthreads();
    if (threadIdx.x < nb) {
        float acc = 0.0f;
        for (int n = 0; n < N; ++n) acc += s_ldj[threadIdx.x * N + n];
        out[(size_t)B * N * 9 + b0 + threadIdx.x] = acc;
    }
}

extern "C" void kernel_launch(void* const* d_in, const int* in_sizes, int n_in,
                              void* d_out, int out_size, void* d_ws, size_t ws_size,
                              hipStream_t stream) {
    const float* rot  = (const float*)d_in[0];
    const float* cond = (const float*)d_in[1];
    const void*  perm = d_in[2];
    float* out = (float*)d_out;

    int items = in_sizes[0] / 9;           // B*N
    int B = out_size - items * 9;          // out = items*9 trot + B ldj
    int N = items / B;

    int grid = (B + 3) / 4;
    mobius_fwd<<<dim3(grid), dim3(448), 0, stream>>>(rot, cond, perm, out, B, N);
}